// Round 9
// baseline (315.886 us; speedup 1.0000x reference)
//
#include <hip/hip_runtime.h>

#define DI __device__ __forceinline__

typedef float  f32x2  __attribute__((ext_vector_type(2)));
typedef float  f32x4  __attribute__((ext_vector_type(4)));
typedef float  f32x16 __attribute__((ext_vector_type(16)));
typedef __bf16 bf16x8 __attribute__((ext_vector_type(8)));
typedef unsigned u32x2 __attribute__((ext_vector_type(2)));
typedef unsigned u32x4 __attribute__((ext_vector_type(4)));

static constexpr int TB   = 2048;   // tokens per batch
static constexpr int NTOK = 8192;   // 4 * 2048
static constexpr int EMB  = 1024;
static constexpr int FQKV = 3072;

// RTNE float -> bf16 bits
DI unsigned short f2bf(float f) {
  union { float f; unsigned u; } v; v.f = f;
  unsigned r = v.u + 0x7FFFu + ((v.u >> 16) & 1u);
  return (unsigned short)(r >> 16);
}

DI unsigned pack2bf(float a, float b) {
#if __has_builtin(__builtin_amdgcn_cvt_pk_bf16_f32)
  typedef __bf16 bf16x2 __attribute__((ext_vector_type(2)));
  bf16x2 r = __builtin_amdgcn_cvt_pk_bf16_f32(a, b);
  return __builtin_bit_cast(unsigned, r);
#else
  unsigned ua = __builtin_bit_cast(unsigned, a) + 0x8000u;
  unsigned ub = __builtin_bit_cast(unsigned, b) + 0x8000u;
  return __builtin_amdgcn_perm(ub, ua, 0x07060302u);
#endif
}

DI void plswap(unsigned& a, unsigned& b) {
#if __has_builtin(__builtin_amdgcn_permlane32_swap)
  u32x2 r = __builtin_amdgcn_permlane32_swap(a, b, false, false);
  a = r.x; b = r.y;
#else
  const bool hi = (threadIdx.x & 32) != 0;
  unsigned ax = (unsigned)__shfl_xor((int)a, 32);
  unsigned bx = (unsigned)__shfl_xor((int)b, 32);
  unsigned na = hi ? bx : a;
  unsigned nb = hi ? b : ax;
  a = na; b = nb;
#endif
}

DI bf16x8 frag4(unsigned a, unsigned b, unsigned c, unsigned d) {
  u32x4 u = {a, b, c, d};
  return __builtin_bit_cast(bf16x8, u);
}

// async global->LDS, 16B per lane; LDS dest = wave-uniform base + lane*16
DI void gload16(const void* g, void* l) {
  __builtin_amdgcn_global_load_lds(
      (__attribute__((address_space(1))) void*)(g),
      (__attribute__((address_space(3))) void*)(l), 16, 0, 0);
}

DI void wait_vm4() { asm volatile("s_waitcnt vmcnt(4)" ::: "memory"); }
DI void wait_vm0() { asm volatile("s_waitcnt vmcnt(0)" ::: "memory"); }
DI void wait_lgkm0() { asm volatile("s_waitcnt lgkmcnt(0)" ::: "memory"); }
DI void rbar()     { __builtin_amdgcn_s_barrier(); }
DI void sfence()   { __builtin_amdgcn_sched_barrier(0); }

// barrier with guaranteed pre-drain of this wave's outstanding DMA ops
DI void syncdrain() {
  __builtin_amdgcn_s_waitcnt(0);
  __syncthreads();
}

// ---------------- fp32 -> bf16 conversion for x, w_qkv, w_out ----------------
__global__ __launch_bounds__(256)
void cvt_kernel(const float4* __restrict__ x, const float4* __restrict__ wq,
                const float4* __restrict__ wo,
                ushort4* __restrict__ xb, ushort4* __restrict__ wqb,
                ushort4* __restrict__ wob) {
  const int nx   = NTOK * EMB / 4;
  const int nq   = FQKV * EMB / 4;
  const int ntot = nx + nq + EMB * EMB / 4;
  for (int i = blockIdx.x * 256 + threadIdx.x; i < ntot; i += gridDim.x * 256) {
    float4 v; ushort4* dst;
    if (i < nx)           { v = x[i];            dst = xb  + i; }
    else if (i < nx + nq) { v = wq[i - nx];      dst = wqb + (i - nx); }
    else                  { v = wo[i - nx - nq]; dst = wob + (i - nx - nq); }
    ushort4 p;
    p.x = f2bf(v.x); p.y = f2bf(v.y); p.z = f2bf(v.z); p.w = f2bf(v.w);
    *dst = p;
  }
}

// ---------------- 256x256 QKV GEMM: faithful m201-style 8-phase --------------
// r9: r4's "8-phase" lacked the template's dual-barrier-per-phase lockstep,
// the lgkmcnt(0)+fence at the barrier->MFMA edge, and correct vmcnt points.
// Faithful port. Derivation (re-checked):
//   buf0 holds even tiles, buf1 odd. Iter j computes e=2j (P1-P4 quadrants
//   (0,0),(0,1),(1,0),(1,1)) then o=2j+1 (P5-P8).
//   Region death: E.A0 after P2, E.B0 after P3, E.A1/E.B1 after P4,
//                 O.* shifted +4.
//   Stage slots (into just-dead regions, guarded by the phase-end barrier):
//     P1: o.A1->buf1   P2: o.B1->buf1   P3: (e+2).A0->buf0  P4: (e+2).B0->buf0
//     P5: (e+2).A1     P6: (e+2).B1     P7: (o+2).A0->buf1  P8: (o+2).B0->buf1
//   Cross-wave DMA visibility: vmcnt at END of P4 guards P5's ds_reads of
//   tile o (younger stages = P3,P4(+own) = 4 instrs -> vmcnt(4); FIFO drains
//   all older). vmcnt at END of P8 guards next-P1's reads of tile e+2
//   (younger = P7,P8 = 4). Epilogue: when the younger stages are dropped
//   (e+2>=NT at j=NIT-1), use vmcnt(0); P8-end wait skipped on last iter.
//   Phase body: {stage; ds_read 12xb128; BARRIER; lgkmcnt(0)+sched_fence
//   (rule 18); setprio(1); 16 MFMA; setprio(0); [vmcnt]; BARRIER}.
// Swizzle: LDS granule g of row r holds src granule g^(r&7) (r&7==srow8 since
// all staged row bases are 8-aligned); reads XOR identically. Verified 0
// conflicts in r2 with the same mapping.
__global__ __launch_bounds__(512, 2)
void gemm_qkv8(const unsigned short* __restrict__ A,
               const unsigned short* __restrict__ Bt,
               const int K,
               unsigned short* __restrict__ qk,
               unsigned short* __restrict__ vT) {
  __shared__ unsigned short sA[2][256 * 64];   // 32KB each
  __shared__ unsigned short sB[2][256 * 64];
  const int tid  = threadIdx.x;
  const int w    = tid >> 6;          // 0..7
  const int l    = tid & 63;
  const int quad = l >> 4;
  const int lr   = l & 15;
  // XCD-aware bijective swizzle (nwg = 12*32 = 384, %8==0)
  const int nwg  = gridDim.x * gridDim.y;
  const int orig = blockIdx.y * gridDim.x + blockIdx.x;
  const int swz  = (orig & 7) * (nwg >> 3) + (orig >> 3);
  const int n0   = (swz % gridDim.x) * 256;
  const int m0   = (swz / gridDim.x) * 256;
  const int wm   = (w >> 2) * 128;    // 2 wave-rows
  const int wn   = (w & 3) * 64;      // 4 wave-cols

  f32x4 acc[8][4];
#pragma unroll
  for (int i = 0; i < 8; ++i)
#pragma unroll
    for (int j = 0; j < 4; ++j) acc[i][j] = {0.f, 0.f, 0.f, 0.f};

  // staging geometry: half-tile = 128 rows x 64 cols x 2B = 16KB = 2 issues
  // of 512thr x 16B. A-half mh rows: {r:(r>>6)&1==mh}; B-half nh: {(r>>5)&1==nh}.
  const int srow8 = l >> 3;                 // 0..7
  const int gsw   = ((l & 7) ^ srow8) * 8;  // pre-swizzled source granule
  int rA[2][2], rB[2][2];
#pragma unroll
  for (int h = 0; h < 2; ++h)
#pragma unroll
    for (int jj = 0; jj < 2; ++jj) {
      const int q0 = w * 16 + jj * 8;
      rA[h][jj] = ((q0 >> 6) << 7) + h * 64 + (q0 & 63);
      rB[h][jj] = ((q0 >> 5) << 6) + h * 32 + (q0 & 31);
    }
  const unsigned short* gAp[2][2];
  const unsigned short* gBp[2][2];
  int ldsA[2][2], ldsB[2][2];
#pragma unroll
  for (int h = 0; h < 2; ++h)
#pragma unroll
    for (int jj = 0; jj < 2; ++jj) {
      gAp[h][jj] = A  + (long)(m0 + rA[h][jj] + srow8) * K + gsw;
      gBp[h][jj] = Bt + (long)(n0 + rB[h][jj] + srow8) * K + gsw;
      ldsA[h][jj] = rA[h][jj] * 64;
      ldsB[h][jj] = rB[h][jj] * 64;
    }

  const int NT  = K >> 6;   // 16 K-tiles of 64
  const int NIT = NT >> 1;  // 8 iterations

#define SG_A(buf, t, h)                                                 \
  do {                                                                  \
    gload16(gAp[h][0] + (t) * 64, &sA[buf][ldsA[h][0]]);                \
    gload16(gAp[h][1] + (t) * 64, &sA[buf][ldsA[h][1]]);                \
  } while (0)
#define SG_B(buf, t, h)                                                 \
  do {                                                                  \
    gload16(gBp[h][0] + (t) * 64, &sB[buf][ldsB[h][0]]);                \
    gload16(gBp[h][1] + (t) * 64, &sB[buf][ldsB[h][1]]);                \
  } while (0)

  // prologue: T0 fully -> buf0, T1.A0,B0 -> buf1 (FIFO: T0 oldest)
  SG_A(0, 0, 0); SG_B(0, 0, 0); SG_A(0, 0, 1); SG_B(0, 0, 1);
  SG_A(1, 1, 0); SG_B(1, 1, 0);
  wait_vm4();   // T0's 8 loads drained (4 younger left in flight)
  sfence();
  rbar();
  sfence();

#define PHASE(bufi, mh, nh, STG, WAITC)                                      \
    do {                                                                     \
      STG;                                                                   \
      bf16x8 afr[4][2], bfr[2][2];                                           \
      const unsigned short* aS = &sA[bufi][0];                               \
      const unsigned short* bS = &sB[bufi][0];                               \
      _Pragma("unroll")                                                      \
      for (int ks = 0; ks < 2; ++ks) {                                       \
        _Pragma("unroll")                                                    \
        for (int nf = 0; nf < 2; ++nf) {                                     \
          const int r = wn + (nh) * 32 + nf * 16 + lr;                       \
          bfr[nf][ks] = *(const bf16x8*)(bS + r * 64 +                       \
                          (((ks * 4 + quad) ^ (r & 7)) * 8));                \
        }                                                                    \
        _Pragma("unroll")                                                    \
        for (int m = 0; m < 4; ++m) {                                        \
          const int ra = wm + (mh) * 64 + m * 16 + lr;                       \
          afr[m][ks] = *(const bf16x8*)(aS + ra * 64 +                       \
                          (((ks * 4 + quad) ^ (ra & 7)) * 8));               \
        }                                                                    \
      }                                                                      \
      rbar();                                                                \
      wait_lgkm0();                                                          \
      sfence();                                                              \
      __builtin_amdgcn_s_setprio(1);                                         \
      _Pragma("unroll")                                                      \
      for (int m = 0; m < 4; ++m)                                            \
        _Pragma("unroll")                                                    \
        for (int nf = 0; nf < 2; ++nf)                                       \
          _Pragma("unroll")                                                  \
          for (int ks = 0; ks < 2; ++ks)                                     \
            acc[(mh) * 4 + m][(nh) * 2 + nf] =                               \
                __builtin_amdgcn_mfma_f32_16x16x32_bf16(                     \
                    afr[m][ks], bfr[nf][ks],                                 \
                    acc[(mh) * 4 + m][(nh) * 2 + nf], 0, 0, 0);              \
      __builtin_amdgcn_s_setprio(0);                                         \
      WAITC;                                                                 \
      rbar();                                                                \
    } while (0)

  for (int j = 0; j < NIT; ++j) {
    const int e = 2 * j, o = 2 * j + 1;
    const bool s2 = (e + 2 < NT);   // stage tiles e+2 / o+2 ?
    PHASE(0, 0, 0, SG_A(1, o, 1), );
    PHASE(0, 0, 1, SG_B(1, o, 1), );
    PHASE(0, 1, 0, if (s2) SG_A(0, e + 2, 0), );
    PHASE(0, 1, 1, if (s2) SG_B(0, e + 2, 0), if (s2) wait_vm4(); else wait_vm0(););
    PHASE(1, 0, 0, if (s2) SG_A(0, e + 2, 1), );
    PHASE(1, 0, 1, if (s2) SG_B(0, e + 2, 1), );
    PHASE(1, 1, 0, if (s2) SG_A(1, o + 2, 0), );
    PHASE(1, 1, 1, if (s2) SG_B(1, o + 2, 0), if (s2) wait_vm4(););
  }
#undef PHASE
#undef SG_A
#undef SG_B

  // QKV epilogue
  if (n0 < 2048) {
    const float qs = (n0 < 1024) ? 0.18033688011112042f : 1.0f;
#pragma unroll
    for (int m = 0; m < 8; ++m) {
      const int row = m0 + wm + m * 16 + quad * 4;
#pragma unroll
      for (int nf = 0; nf < 4; ++nf) {
        const int col = n0 + wn + nf * 16 + lr;
#pragma unroll
        for (int r = 0; r < 4; ++r)
          qk[(long)(row + r) * 2048 + col] = f2bf(acc[m][nf][r] * qs);
      }
    }
  } else {
#pragma unroll
    for (int m = 0; m < 8; ++m) {
      const int tok = m0 + wm + m * 16 + quad * 4;
      const int bb  = tok >> 11, tt = tok & 2047;
#pragma unroll
      for (int nf = 0; nf < 4; ++nf) {
        const int fv = n0 - 2048 + wn + nf * 16 + lr;  // h*64+d
        ushort4 p;
        p.x = f2bf(acc[m][nf][0]); p.y = f2bf(acc[m][nf][1]);
        p.z = f2bf(acc[m][nf][2]); p.w = f2bf(acc[m][nf][3]);
        *(ushort4*)(vT + ((long)(bb * 1024 + fv)) * 2048 + tt) = p;
      }
    }
  }
}

// ---------------- 128x64 bf16 out-projection GEMM (frozen from r8) ----------
__global__ __launch_bounds__(256, 4)
void gemm_out(const unsigned short* __restrict__ A,
              const unsigned short* __restrict__ Bt,
              const int K,
              float* __restrict__ outp) {
  __shared__ unsigned short sA[128 * 32];   // 8KB
  __shared__ unsigned short sB[64 * 32];    // 4KB
  const int tid  = threadIdx.x;
  const int w    = tid >> 6;
  const int l    = tid & 63;
  const int quad = l >> 4;
  const int lr   = l & 15;
  const int nwg  = gridDim.x * gridDim.y;   // 1024, %8==0
  const int orig = blockIdx.y * gridDim.x + blockIdx.x;
  const int swzb = (orig & 7) * (nwg >> 3) + (orig >> 3);
  const int n0   = (swzb % gridDim.x) * 64;
  const int m0   = (swzb / gridDim.x) * 128;
  const int wm   = (w >> 1) * 64;
  const int wn   = (w & 1) * 32;

  f32x4 acc[4][2];
#pragma unroll
  for (int i = 0; i < 4; ++i)
#pragma unroll
    for (int j = 0; j < 2; ++j) acc[i][j] = {0.f, 0.f, 0.f, 0.f};

  const int srow = l >> 2;
  const int sg   = (l & 3) ^ ((l >> 3) & 3);
  const unsigned short* gA = A  + (long)(m0 + w * 32 + srow) * K + sg * 8;
  const unsigned short* gB = Bt + (long)(n0 + w * 16 + srow) * K + sg * 8;
  unsigned short* lA = sA + w * 1024;
  unsigned short* lB = sB + w * 512;
  const int swz = (lr >> 1) & 3;

  for (int k0 = 0; k0 < K; k0 += 32) {
    gload16(gA + k0,          lA);
    gload16(gA + k0 + 16 * K, lA + 512);
    gload16(gB + k0,          lB);
    syncdrain();
    bf16x8 af[4], bfr[2];
#pragma unroll
    for (int rt = 0; rt < 4; ++rt)
      af[rt] = *(const bf16x8*)(sA + (wm + rt * 16 + lr) * 32 + (quad ^ swz) * 8);
#pragma unroll
    for (int ct = 0; ct < 2; ++ct)
      bfr[ct] = *(const bf16x8*)(sB + (wn + ct * 16 + lr) * 32 + (quad ^ swz) * 8);
#pragma unroll
    for (int rt = 0; rt < 4; ++rt)
#pragma unroll
      for (int ct = 0; ct < 2; ++ct)
        acc[rt][ct] = __builtin_amdgcn_mfma_f32_16x16x32_bf16(af[rt], bfr[ct],
                                                              acc[rt][ct], 0, 0, 0);
    __syncthreads();
  }

#pragma unroll
  for (int rt = 0; rt < 4; ++rt) {
    const int row = m0 + wm + rt * 16 + quad * 4;
#pragma unroll
    for (int ct = 0; ct < 2; ++ct) {
      const int col = n0 + wn + ct * 16 + lr;
#pragma unroll
      for (int r = 0; r < 4; ++r)
        outp[(long)(row + r) * 1024 + col] = acc[rt][ct][r];
    }
  }
}

// ---------------- flash attention (frozen: ~91us) ---------------------------
__global__ __launch_bounds__(256, 4)
void attn_kernel(const unsigned short* __restrict__ qk,
                 const unsigned short* __restrict__ vT,
                 unsigned short* __restrict__ attnb) {
  __shared__ unsigned short sK[2][64 * 64];
  __shared__ unsigned short sV[2][64 * 64];
  const int tid = threadIdx.x;
  const int w   = tid >> 6;
  const int l   = tid & 63;
  const int l31 = l & 31;
  const int lh  = l >> 5;
  const int h8  = lh * 8;
  const int bh  = blockIdx.x;
  const int hh  = bh & 15;
  const long tokbase = (long)(bh >> 4) * TB;
  const int qbase = blockIdx.y * 128 + w * 32;

  bf16x8 qf[4];
  {
    const unsigned short* qptr = qk + (tokbase + qbase + l31) * 2048 + hh * 64 + h8;
#pragma unroll
    for (int s = 0; s < 4; ++s) qf[s] = *(const bf16x8*)(qptr + s * 16);
  }

  const int srow = l >> 3;
  const int g    = (l & 7) ^ srow;
  const unsigned short* kbase =
      qk + (tokbase + w * 16 + srow) * 2048 + 1024 + hh * 64 + g * 8;
  const unsigned short* vbase =
      vT + ((long)bh * 64 + w * 16 + srow) * 2048 + g * 8;

  f32x16 oacc[2] = {{}, {}};
  f32x2 lp2 = {0.f, 0.f};

  gload16(kbase,            &sK[0][(w * 16 + 0) * 64]);
  gload16(kbase + 8 * 2048, &sK[0][(w * 16 + 8) * 64]);
  gload16(vbase,            &sV[0][(w * 16 + 0) * 64]);
  gload16(vbase + 8 * 2048, &sV[0][(w * 16 + 8) * 64]);

  for (int t = 0; t < 32; ++t) {
    const int buf = t & 1;
    if (t + 1 < 32) {
      const int k0 = (t + 1) * 64;
      const int nb = buf ^ 1;
      gload16(kbase + (long)k0 * 2048,            &sK[nb][(w * 16 + 0) * 64]);
      gload16(kbase + (long)k0 * 2048 + 8 * 2048, &sK[nb][(w * 16 + 8) * 64]);
      gload16(vbase + k0,                         &sV[nb][(w * 16 + 0) * 64]);
      gload16(vbase + k0 + 8 * 2048,              &sV[nb][(w * 16 + 8) * 64]);
      wait_vm4();
    } else {
      wait_vm0();
    }
    sfence();
    rbar();
    sfence();
    const unsigned short* bK = sK[buf];
    const unsigned short* bV = sV[buf];

#pragma unroll
    for (int G = 0; G < 2; ++G) {
      f32x16 sacc = {};
      __builtin_amdgcn_s_setprio(1);
#pragma unroll
      for (int s = 0; s < 4; ++s) {
        const int key = G * 32 + l31;
        const int p   = (s * 2 + lh) ^ (key & 7);
        const bf16x8 kf = *(const bf16x8*)(bK + key * 64 + p * 8);
        sacc = __builtin_amdgcn_mfma_f32_32x32x16_bf16(kf, qf[s], sacc, 0, 0, 0);
      }
      __builtin_amdgcn_s_setprio(0);
      float e[16];
#pragma unroll
      for (int i = 0; i < 16; ++i) e[i] = __builtin_amdgcn_exp2f(sacc[i]);
#pragma unroll
      for (int i = 0; i < 8; ++i) {
        f32x2 pr = {e[2 * i], e[2 * i + 1]};
        lp2 += pr;
      }
      unsigned d[8];
#pragma unroll
      for (int i = 0; i < 8; ++i) d[i] = pack2bf(e[2 * i], e[2 * i + 1]);
      plswap(d[0], d[2]); plswap(d[1], d[3]);
      plswap(d[4], d[6]); plswap(d[5], d[7]);
      bf16x8 pp[2];
      pp[0] = frag4(d[0], d[1], d[2], d[3]);
      pp[1] = frag4(d[4], d[5], d[6], d[7]);
      __builtin_amdgcn_s_setprio(1);
#pragma unroll
      for (int sub = 0; sub < 2; ++sub) {
        const int gt  = (G * 2 + sub) * 2 + lh;
        const int d0r = l31, d1r = 32 + l31;
        const bf16x8 vf0 = *(const bf16x8*)(bV + d0r * 64 + ((gt ^ (d0r & 7))) * 8);
        const bf16x8 vf1 = *(const bf16x8*)(bV + d1r * 64 + ((gt ^ (d1r & 7))) * 8);
        oacc[0] = __builtin_amdgcn_mfma_f32_32x32x16_bf16(pp[sub], vf0, oacc[0], 0, 0, 0);
        oacc[1] = __builtin_amdgcn_mfma_f32_32x32x16_bf16(pp[sub], vf1, oacc[1], 0, 0, 0);
      }
      __builtin_amdgcn_s_setprio(0);
    }
    sfence();
    rbar();
  }

  const float lp = lp2.x + lp2.y;
  const float fs = lp + __shfl_xor(lp, 32);
  const float rc = 1.0f / fs;
#pragma unroll
  for (int r = 0; r < 16; ++r) {
    const int row = (r & 3) + 8 * (r >> 2) + 4 * lh;
    const float sc = __shfl(rc, row);
    const long base = (tokbase + qbase + row) * 1024 + hh * 64;
    attnb[base + l31]      = f2bf(oacc[0][r] * sc);
    attnb[base + 32 + l31] = f2bf(oacc[1][r] * sc);
  }
}

// ---------------------------------------------------------------------------
extern "C" void kernel_launch(void* const* d_in, const int* in_sizes, int n_in,
                              void* d_out, int out_size, void* d_ws, size_t ws_size,
                              hipStream_t stream) {
  const float* x    = (const float*)d_in[0];
  const float* wqkv = (const float*)d_in[1];
  const float* wout = (const float*)d_in[2];
  float* outp = (float*)d_out;

  unsigned short* xb    = (unsigned short*)d_ws;          // 8192*1024
  unsigned short* wqkvb = xb    + (long)NTOK * EMB;       // 3072*1024
  unsigned short* woutb = wqkvb + (long)FQKV * EMB;       // 1024*1024
  unsigned short* qkb   = woutb + (long)EMB * EMB;        // 8192*2048 (Q|K)
  unsigned short* vTb   = qkb   + (long)NTOK * 2048;      // 4*16*64*2048
  unsigned short* attnb = vTb   + (long)4 * 16 * 64 * TB; // 8192*1024

  cvt_kernel<<<3072, 256, 0, stream>>>(
      (const float4*)x, (const float4*)wqkv, (const float4*)wout,
      (ushort4*)xb, (ushort4*)wqkvb, (ushort4*)woutb);

  // QKV projection: 256^2 8-phase template, 384 blocks
  gemm_qkv8<<<dim3(12, 32), 512, 0, stream>>>(xb, wqkvb, EMB, qkb, vTb);

  attn_kernel<<<dim3(64, 16), 256, 0, stream>>>(qkb, vTb, attnb);

  // output projection: 128x64 tiles, 1024 blocks (frozen from r8)
  gemm_out<<<dim3(16, 64), 256, 0, stream>>>(attnb, woutb, EMB, outp);
}